// Round 6
// baseline (175.595 us; speedup 1.0000x reference)
//
#include <hip/hip_runtime.h>

#define N_NODES 6000
#define N_EDGES 48000
#define NODE_TYPE_SIZE 9
#define OBSTACLE 1
#define RADIUS2 0.0009f
#define EPS_F 1e-8f

// ---- output layout (flat concat, return order) ----
// node_out : [6000,12]        offset 0           size 72,000
// mesh_out : [48000,7]        offset 72,000      size 336,000
// world_out: [6000,6000,4]    offset 408,000     size 144,000,000
// agg      : [6000,7]         offset 144,408,000 size 42,000
#define OFF_NODE  0
#define OFF_MESH  72000
#define OFF_WORLD 408000
#define OFF_AGG   144408000

// aux thread partitions
#define AUX_NODE_END 72000                    // node_out elements
#define AUX_AGG_END  (72000 + 42000)          // + agg elements
#define AUX_TBL_END  (72000 + 42000 + 6000)   // + per-node table entries

#define TI 128            // i-tile per block in k_pairs
#define WORLD_N4 36000000 // world_out float4 count (6000*6000)
#define ZBLK 256          // k_zero blocks (1 per CU)
#define ZSLAB (WORLD_N4 / ZBLK)  // 140625 float4 per block, exact

// node_out features + agg zeroing + packed pair-test table build, one launch.
// tbl[j] = (x, y, z, sq_j) with sq_j poisoned to 1e30 when node j is an
// obstacle (reference masks edges INTO obstacle nodes only, i.e. the j role).
__global__ void k_aux(const float* __restrict__ wp, const float* __restrict__ pwp,
                      const int* __restrict__ nt, const float* __restrict__ nmean,
                      const float* __restrict__ nstd, float* __restrict__ node_out,
                      float* __restrict__ agg, float4* __restrict__ tbl) {
    int t = blockIdx.x * blockDim.x + threadIdx.x;
    if (t < AUX_NODE_END) {
        int n = t / 12;
        int f = t - n * 12;
        float feat;
        if (f < 3) feat = wp[n * 3 + f] - pwp[n * 3 + f];
        else       feat = (nt[n] == f - 3) ? 1.0f : 0.0f;
        node_out[t] = (feat - nmean[f]) / fmaxf(nstd[f], EPS_F);
    } else if (t < AUX_AGG_END) {
        agg[t - AUX_NODE_END] = 0.0f;
    } else if (t < AUX_TBL_END) {
        int j = t - AUX_AGG_END;
        float x = wp[3 * j + 0], y = wp[3 * j + 1], z = wp[3 * j + 2];
        float sq = x * x + y * y + z * z;
        if (nt[j] == OBSTACLE) sq = 1e30f;
        tbl[j] = make_float4(x, y, z, sq);
    }
}

__global__ void k_mesh(const float* __restrict__ wp, const float* __restrict__ mp,
                       const int* __restrict__ senders, const int* __restrict__ receivers,
                       const float* __restrict__ mean, const float* __restrict__ stdv,
                       float* __restrict__ mesh_out, float* __restrict__ agg) {
    int e = blockIdx.x * blockDim.x + threadIdx.x;
    if (e >= N_EDGES) return;
    int s = senders[e];
    int r = receivers[e];
    float rwx = wp[3 * s + 0] - wp[3 * r + 0];
    float rwy = wp[3 * s + 1] - wp[3 * r + 1];
    float rwz = wp[3 * s + 2] - wp[3 * r + 2];
    float nrw = sqrtf(rwx * rwx + rwy * rwy + rwz * rwz);
    float rmx = mp[2 * s + 0] - mp[2 * r + 0];
    float rmy = mp[2 * s + 1] - mp[2 * r + 1];
    float nrm = sqrtf(rmx * rmx + rmy * rmy);
    float feats[7] = {rwx, rwy, rwz, nrw, rmx, rmy, nrm};
    #pragma unroll
    for (int k = 0; k < 7; ++k) {
        float o = (feats[k] - mean[k]) / fmaxf(stdv[k], EPS_F);
        mesh_out[e * 7 + k] = o;
        atomicAdd(&agg[r * 7 + k], o);
    }
}

// Zero-fill replicating the 6.8 TB/s rocclr fill's configuration signature
// (11% occupancy = ~1 block/CU, 4 waves, long-lived blocks): 256 blocks,
// each owning one CONTIGUOUS 2.25MB slab, inner loop advancing 4KB per
// iteration -> one linear write stream per CU. Evidence (r1-r5): the SAME
// rocclr fill kernel runs 1.6 TB/s on a 576MB memset (grid scaled 4x down)
// but 6.8 TB/s on the 2.3GB poison -> rate tracks stream config, and the
// fast config is few long-lived per-CU-linear streams, which none of the
// previous 6 variants reproduced.
__global__ void k_zero(float4* __restrict__ p) {
    const float4 z = make_float4(0.0f, 0.0f, 0.0f, 0.0f);
    const size_t base = (size_t)blockIdx.x * ZSLAB;
    const size_t end  = base + ZSLAB;
    #pragma unroll 8
    for (size_t i = base + threadIdx.x; i < end; i += 256) {
        p[i] = z;
    }
}

// Sparse pair-scan: world_out already zeroed by k_zero. Tests all 36M pairs
// (compute-only, LDS-broadcast i-tile) and writes only the ~4K hits.
// Numerics deliberately identical to the round-0 dense kernel:
// d2 = sqi + tbl[j].w - 2*dot, so borderline-threshold membership cannot flip.
__global__ void k_pairs(const float4* __restrict__ tbl, const float* __restrict__ mean,
                        const float* __restrict__ stdv, float4* __restrict__ world_out) {
    __shared__ float4 si[TI];
    const int i0 = blockIdx.y * TI;
    const int ni = (N_NODES - i0 < TI) ? (N_NODES - i0) : TI;
    if (threadIdx.x < ni) si[threadIdx.x] = tbl[i0 + threadIdx.x];
    __syncthreads();

    const int j = blockIdx.x * 256 + threadIdx.x;
    if (j >= N_NODES) return;
    const float4 pj = tbl[j];
    if (pj.w > 1e29f) return;  // obstacle j: no edges into j, nothing to write

    const float m0 = mean[0], m1 = mean[1], m2 = mean[2], m3 = mean[3];
    const float s0 = fmaxf(stdv[0], EPS_F), s1 = fmaxf(stdv[1], EPS_F);
    const float s2 = fmaxf(stdv[2], EPS_F), s3 = fmaxf(stdv[3], EPS_F);

    #pragma unroll 4
    for (int k = 0; k < ni; ++k) {
        float4 pi = si[k];
        float sqi = pi.x * pi.x + pi.y * pi.y + pi.z * pi.z;
        float dot = pi.x * pj.x + pi.y * pj.y + pi.z * pj.z;
        float d2 = sqi + pj.w - 2.0f * dot;
        int i = i0 + k;
        if (d2 < RADIUS2 && i != j) {
            float rx = pj.x - pi.x, ry = pj.y - pi.y, rz = pj.z - pi.z;
            float nrm = sqrtf(rx * rx + ry * ry + rz * rz);
            float4 v;
            v.x = (rx  - m0) / s0;
            v.y = (ry  - m1) / s1;
            v.z = (rz  - m2) / s2;
            v.w = (nrm - m3) / s3;
            world_out[(size_t)i * N_NODES + j] = v;
        }
    }
}

// Drop existing mesh edges: unconditionally zero world_out[s][r]. After k_pairs.
__global__ void k_edge_zero(const int* __restrict__ senders, const int* __restrict__ receivers,
                            float4* __restrict__ world_out) {
    int e = blockIdx.x * blockDim.x + threadIdx.x;
    if (e >= N_EDGES) return;
    world_out[(size_t)senders[e] * N_NODES + receivers[e]] = make_float4(0.0f, 0.0f, 0.0f, 0.0f);
}

extern "C" void kernel_launch(void* const* d_in, const int* in_sizes, int n_in,
                              void* d_out, int out_size, void* d_ws, size_t ws_size,
                              hipStream_t stream) {
    const float* wp    = (const float*)d_in[0];
    const float* pwp   = (const float*)d_in[1];
    const float* mp    = (const float*)d_in[2];
    const int*   nt    = (const int*)d_in[3];
    const int*   snd   = (const int*)d_in[4];
    const int*   rcv   = (const int*)d_in[5];
    const float* nmean = (const float*)d_in[6];
    const float* nstd  = (const float*)d_in[7];
    const float* mmean = (const float*)d_in[8];
    const float* mstd  = (const float*)d_in[9];
    const float* wmean = (const float*)d_in[10];
    const float* wstd  = (const float*)d_in[11];

    float* out       = (float*)d_out;
    float* node_out  = out + OFF_NODE;
    float* mesh_out  = out + OFF_MESH;
    float* world_out = out + OFF_WORLD;
    float* agg       = out + OFF_AGG;
    float4* tbl      = (float4*)d_ws;  // 6000 * 16B = 96 KB

    // 1. node features + agg zero + pair-table build
    k_aux<<<(AUX_TBL_END + 255) / 256, 256, 0, stream>>>(
        wp, pwp, nt, nmean, nstd, node_out, agg, tbl);

    // 2. mesh edge features + scatter-add (agg zeroed by k_aux)
    k_mesh<<<(N_EDGES + 255) / 256, 256, 0, stream>>>(
        wp, mp, snd, rcv, mmean, mstd, mesh_out, agg);

    // 3. zero the dense world_out: 256 long-lived blocks, one linear
    //    2.25MB stream per CU (rocclr 6.8 TB/s fill signature)
    k_zero<<<ZBLK, 256, 0, stream>>>((float4*)world_out);

    // 4. compute-only pair scan, writes only the ~4K in-radius entries
    dim3 pgrid((N_NODES + 255) / 256, (N_NODES + TI - 1) / TI);
    k_pairs<<<pgrid, 256, 0, stream>>>(tbl, wmean, wstd, (float4*)world_out);

    // 5. drop existing mesh edges (after k_pairs)
    k_edge_zero<<<(N_EDGES + 255) / 256, 256, 0, stream>>>(snd, rcv, (float4*)world_out);
}

// Round 7
// 142.282 us; speedup vs baseline: 1.2341x; 1.2341x over previous
//
#include <hip/hip_runtime.h>

#define N_NODES 6000
#define N_EDGES 48000
#define NODE_TYPE_SIZE 9
#define OBSTACLE 1
#define RADIUS2 0.0009f
#define EPS_F 1e-8f

// ---- output layout (flat concat, return order) ----
// node_out : [6000,12]        offset 0           size 72,000
// mesh_out : [48000,7]        offset 72,000      size 336,000
// world_out: [6000,6000,4]    offset 408,000     size 144,000,000
// agg      : [6000,7]         offset 144,408,000 size 42,000
#define OFF_NODE  0
#define OFF_MESH  72000
#define OFF_WORLD 408000
#define OFF_AGG   144408000

// aux thread partitions
#define AUX_NODE_END 72000                    // node_out elements
#define AUX_AGG_END  (72000 + 42000)          // + agg elements
#define AUX_TBL_END  (72000 + 42000 + 6000)   // + per-node table entries

#define JPT 8   // j's per thread in k_world

// native vector type usable with __builtin_nontemporal_store
typedef float floatx4 __attribute__((ext_vector_type(4)));

// Session evidence (r0-r6): the dense 576MB world_out write is the roofline
// term, and our-kernel writes on this arena cap at ~4.4 TB/s effective
// regardless of stream shape (7 configs tested: grid-stride/chunked/tiny-
// block/per-CU-slab, nt/plain, occupancy 11%-100% -> all 3.8-4.4 TB/s;
// only the harness's own 2.3GB arena-wide poison fill reaches 6.8, not
// reproducible from our launches on d_out). The fused single-pass JPT=8
// kernel below sits AT that ceiling: 576MB/4.4TB/s ~= 131us + ~10us for
// the small kernels = 141.8us measured.

// node_out features + agg zeroing + packed pair-test table build, one launch.
// tbl[j] = (x, y, z, sq_j) with sq_j poisoned to 1e30 when node j is an
// obstacle (reference masks edges INTO obstacle nodes only, i.e. the j role).
__global__ void k_aux(const float* __restrict__ wp, const float* __restrict__ pwp,
                      const int* __restrict__ nt, const float* __restrict__ nmean,
                      const float* __restrict__ nstd, float* __restrict__ node_out,
                      float* __restrict__ agg, float4* __restrict__ tbl) {
    int t = blockIdx.x * blockDim.x + threadIdx.x;
    if (t < AUX_NODE_END) {
        int n = t / 12;
        int f = t - n * 12;
        float feat;
        if (f < 3) feat = wp[n * 3 + f] - pwp[n * 3 + f];
        else       feat = (nt[n] == f - 3) ? 1.0f : 0.0f;
        node_out[t] = (feat - nmean[f]) / fmaxf(nstd[f], EPS_F);
    } else if (t < AUX_AGG_END) {
        agg[t - AUX_NODE_END] = 0.0f;
    } else if (t < AUX_TBL_END) {
        int j = t - AUX_AGG_END;
        float x = wp[3 * j + 0], y = wp[3 * j + 1], z = wp[3 * j + 2];
        float sq = x * x + y * y + z * z;
        if (nt[j] == OBSTACLE) sq = 1e30f;
        tbl[j] = make_float4(x, y, z, sq);
    }
}

__global__ void k_mesh(const float* __restrict__ wp, const float* __restrict__ mp,
                       const int* __restrict__ senders, const int* __restrict__ receivers,
                       const float* __restrict__ mean, const float* __restrict__ stdv,
                       float* __restrict__ mesh_out, float* __restrict__ agg) {
    int e = blockIdx.x * blockDim.x + threadIdx.x;
    if (e >= N_EDGES) return;
    int s = senders[e];
    int r = receivers[e];
    float rwx = wp[3 * s + 0] - wp[3 * r + 0];
    float rwy = wp[3 * s + 1] - wp[3 * r + 1];
    float rwz = wp[3 * s + 2] - wp[3 * r + 2];
    float nrw = sqrtf(rwx * rwx + rwy * rwy + rwz * rwz);
    float rmx = mp[2 * s + 0] - mp[2 * r + 0];
    float rmy = mp[2 * s + 1] - mp[2 * r + 1];
    float nrm = sqrtf(rmx * rmx + rmy * rmy);
    float feats[7] = {rwx, rwy, rwz, nrw, rmx, rmy, nrm};
    #pragma unroll
    for (int k = 0; k < 7; ++k) {
        float o = (feats[k] - mean[k]) / fmaxf(stdv[k], EPS_F);
        mesh_out[e * 7 + k] = o;
        atomicAdd(&agg[r * 7 + k], o);
    }
}

// Fused dense world-edge pass: one thread handles JPT j's at wave-coalesced
// stride so every store instruction is a contiguous 1 KB/wave. i is
// block-uniform -> pi/means scalarized. tbl is 96 KB -> L1/L2 resident.
__global__ void k_world(const float4* __restrict__ tbl, const float* __restrict__ mean,
                        const float* __restrict__ stdv, floatx4* __restrict__ world_out) {
    const int i = blockIdx.y;
    const int j_base = blockIdx.x * (256 * JPT) + threadIdx.x;
    const float4 pi = tbl[i];
    // true sq for the i role (table .w may be obstacle-poisoned; that mask
    // only applies to the j role per the reference)
    const float sqi = pi.x * pi.x + pi.y * pi.y + pi.z * pi.z;
    const float m0 = mean[0], m1 = mean[1], m2 = mean[2], m3 = mean[3];
    const float s0 = fmaxf(stdv[0], EPS_F), s1 = fmaxf(stdv[1], EPS_F);
    const float s2 = fmaxf(stdv[2], EPS_F), s3 = fmaxf(stdv[3], EPS_F);
    floatx4* __restrict__ row = world_out + (size_t)i * N_NODES;
    #pragma unroll
    for (int k = 0; k < JPT; ++k) {
        int j = j_base + k * 256;
        if (j < N_NODES) {
            float4 pj = tbl[j];
            float dot = pi.x * pj.x + pi.y * pj.y + pi.z * pj.z;
            float d2 = sqi + pj.w - 2.0f * dot;
            floatx4 v = (floatx4){0.0f, 0.0f, 0.0f, 0.0f};
            if (d2 < RADIUS2 && i != j) {
                float rx = pj.x - pi.x, ry = pj.y - pi.y, rz = pj.z - pi.z;
                float nrm = sqrtf(rx * rx + ry * ry + rz * rz);
                v.x = (rx  - m0) / s0;
                v.y = (ry  - m1) / s1;
                v.z = (rz  - m2) / s2;
                v.w = (nrm - m3) / s3;
            }
            __builtin_nontemporal_store(v, &row[j]);
        }
    }
}

// Drop existing mesh edges: unconditionally zero world_out[s][r]. After k_world.
__global__ void k_edge_zero(const int* __restrict__ senders, const int* __restrict__ receivers,
                            float4* __restrict__ world_out) {
    int e = blockIdx.x * blockDim.x + threadIdx.x;
    if (e >= N_EDGES) return;
    world_out[(size_t)senders[e] * N_NODES + receivers[e]] = make_float4(0.0f, 0.0f, 0.0f, 0.0f);
}

extern "C" void kernel_launch(void* const* d_in, const int* in_sizes, int n_in,
                              void* d_out, int out_size, void* d_ws, size_t ws_size,
                              hipStream_t stream) {
    const float* wp    = (const float*)d_in[0];
    const float* pwp   = (const float*)d_in[1];
    const float* mp    = (const float*)d_in[2];
    const int*   nt    = (const int*)d_in[3];
    const int*   snd   = (const int*)d_in[4];
    const int*   rcv   = (const int*)d_in[5];
    const float* nmean = (const float*)d_in[6];
    const float* nstd  = (const float*)d_in[7];
    const float* mmean = (const float*)d_in[8];
    const float* mstd  = (const float*)d_in[9];
    const float* wmean = (const float*)d_in[10];
    const float* wstd  = (const float*)d_in[11];

    float* out       = (float*)d_out;
    float* node_out  = out + OFF_NODE;
    float* mesh_out  = out + OFF_MESH;
    float* world_out = out + OFF_WORLD;
    float* agg       = out + OFF_AGG;
    float4* tbl      = (float4*)d_ws;  // 6000 * 16B = 96 KB

    // 1. node features + agg zero + pair-table build
    k_aux<<<(AUX_TBL_END + 255) / 256, 256, 0, stream>>>(
        wp, pwp, nt, nmean, nstd, node_out, agg, tbl);

    // 2. mesh edge features + scatter-add (agg zeroed by k_aux)
    k_mesh<<<(N_EDGES + 255) / 256, 256, 0, stream>>>(
        wp, mp, snd, rcv, mmean, mstd, mesh_out, agg);

    // 3. fused dense world-edge stream (the roofline cost)
    dim3 wgrid((N_NODES + 256 * JPT - 1) / (256 * JPT), N_NODES);
    k_world<<<wgrid, 256, 0, stream>>>(tbl, wmean, wstd, (floatx4*)world_out);

    // 4. drop existing mesh edges (after k_world)
    k_edge_zero<<<(N_EDGES + 255) / 256, 256, 0, stream>>>(snd, rcv, (float4*)world_out);
}